// Round 6
// baseline (380.885 us; speedup 1.0000x reference)
//
#include <hip/hip_runtime.h>
#include <hip/hip_fp16.h>
#include <math.h>

#define NNODES 100000
#define NEG_SLOPE 0.2f
#define FIN 500
#define KP 512     // padded K
#define HID 128    // heads*hidden
#define NH 4

typedef __attribute__((ext_vector_type(8))) short short8v;
typedef __attribute__((ext_vector_type(4))) float f32x4;

__device__ __forceinline__ float lrelu(float x) { return x > 0.f ? x : NEG_SLOPE * x; }

__device__ __forceinline__ float sel4(float a0, float a1, float a2, float a3, int h) {
  float r = a0;
  r = (h == 1) ? a1 : r;
  r = (h == 2) ? a2 : r;
  r = (h == 3) ? a3 : r;
  return r;
}

__device__ __forceinline__ unsigned short f32_to_bf16_rn(float f) {
  unsigned u = __float_as_uint(f);
  unsigned r = u + 0x7fffu + ((u >> 16) & 1u);
  return (unsigned short)(r >> 16);
}
__device__ __forceinline__ float bf16_to_f32(unsigned short h) {
  return __uint_as_float(((unsigned)h) << 16);
}

// ---------------- W1 -> transposed bf16 hi/lo [128][512] ----------------
__global__ __launch_bounds__(256) void convert_w1_kernel(const float* __restrict__ W1,
                                                         short* __restrict__ BhT,
                                                         short* __restrict__ BlT) {
  int idx = blockIdx.x * 256 + threadIdx.x;  // 65536
  int n = idx >> 9, k = idx & 511;
  float v = (k < FIN) ? W1[k * HID + n] : 0.f;
  unsigned short hb = f32_to_bf16_rn(v);
  float lo = v - bf16_to_f32(hb);
  BhT[n * KP + k] = (short)hb;
  BlT[n * KP + k] = (short)f32_to_bf16_rn(lo);
}

// ---------------- GEMM1: barrier-free reg-direct split-bf16 MFMA ----------------
// Block 256 = 4 independent waves; wave tile 32x64; grid = 782*2 (col halves).
__global__ __launch_bounds__(256, 3) void gemm1_mfma_kernel(const float* __restrict__ A,
                                                            const short* __restrict__ BhT,
                                                            const short* __restrict__ BlT,
                                                            __half* __restrict__ z1h) {
  const int t = threadIdx.x;
  const int w = t >> 6, lane = t & 63;
  const int bm = (blockIdx.x >> 1) * 128 + w * 32;   // wave's 32-row base
  const int c0 = (blockIdx.x & 1) * 64;              // column half
  const int fr = lane & 15, ko = lane >> 4;

  // clamped A row pointers for the two 16-row fragments (OOB rows -> row N-1, never stored)
  const int r0 = min(bm + fr, NNODES - 1);
  const int r1 = min(bm + 16 + fr, NNODES - 1);
  const float* pA0 = A + (size_t)r0 * FIN + ko * 8;
  const float* pA1 = A + (size_t)r1 * FIN + ko * 8;
  const short* pB0h = BhT + (size_t)(c0 + 0 * 16 + fr) * KP + ko * 8;
  const short* pB1h = BhT + (size_t)(c0 + 1 * 16 + fr) * KP + ko * 8;
  const short* pB2h = BhT + (size_t)(c0 + 2 * 16 + fr) * KP + ko * 8;
  const short* pB3h = BhT + (size_t)(c0 + 3 * 16 + fr) * KP + ko * 8;
  const short* pB0l = BlT + (size_t)(c0 + 0 * 16 + fr) * KP + ko * 8;
  const short* pB1l = BlT + (size_t)(c0 + 1 * 16 + fr) * KP + ko * 8;
  const short* pB2l = BlT + (size_t)(c0 + 2 * 16 + fr) * KP + ko * 8;
  const short* pB3l = BlT + (size_t)(c0 + 3 * 16 + fr) * KP + ko * 8;

  f32x4 acc[2][4];
#pragma unroll
  for (int i = 0; i < 2; i++)
#pragma unroll
    for (int j = 0; j < 4; j++) acc[i][j] = (f32x4){0.f, 0.f, 0.f, 0.f};

  // cur/nxt register sets (named, statically indexed)
  f32x4 a0A, a0B, a1A, a1B;          // cur A f32 (rows frag0, frag1)
  f32x4 n0A, n0B, n1A, n1B;          // nxt A f32
  short8v b0h, b1h, b2h, b3h, b0l, b1l, b2l, b3l;
  short8v m0h, m1h, m2h, m3h, m0l, m1l, m2l, m3l;

#define LOADA_FAST(K0, d0A, d0B, d1A, d1B)          \
  do {                                              \
    d0A = *(const f32x4*)(pA0 + (K0));              \
    d0B = *(const f32x4*)(pA0 + (K0) + 4);          \
    d1A = *(const f32x4*)(pA1 + (K0));              \
    d1B = *(const f32x4*)(pA1 + (K0) + 4);          \
  } while (0)

  // boundary step K0=480: element k = 480+ko*8+i valid iff < FIN
#define LOADA_EDGE(d0A, d0B, d1A, d1B)                            \
  do {                                                            \
    _Pragma("unroll")                                             \
    for (int i = 0; i < 4; i++) {                                 \
      int kk = 480 + ko * 8 + i;                                  \
      d0A[i] = (kk < FIN) ? pA0[480 + i] : 0.f;                   \
      d1A[i] = (kk < FIN) ? pA1[480 + i] : 0.f;                   \
      d0B[i] = (kk + 4 < FIN) ? pA0[484 + i] : 0.f;               \
      d1B[i] = (kk + 4 < FIN) ? pA1[484 + i] : 0.f;               \
    }                                                             \
  } while (0)

#define LOADB(K0, h0, h1, h2, h3, l0, l1, l2, l3)   \
  do {                                              \
    h0 = *(const short8v*)(pB0h + (K0));            \
    h1 = *(const short8v*)(pB1h + (K0));            \
    h2 = *(const short8v*)(pB2h + (K0));            \
    h3 = *(const short8v*)(pB3h + (K0));            \
    l0 = *(const short8v*)(pB0l + (K0));            \
    l1 = *(const short8v*)(pB1l + (K0));            \
    l2 = *(const short8v*)(pB2l + (K0));            \
    l3 = *(const short8v*)(pB3l + (K0));            \
  } while (0)

  // trunc-split: hi = upper16(v), lo = trunc16(v - hi_f32); exact to ~2^-16
#define CONV_MFMA(s0A, s0B, s1A, s1B, h0, h1, h2, h3, l0, l1, l2, l3)          \
  do {                                                                         \
    short8v fh0, fl0, fh1, fl1;                                                \
    _Pragma("unroll")                                                          \
    for (int i = 0; i < 4; i++) {                                              \
      unsigned u = __float_as_uint(s0A[i]);                                    \
      fh0[i] = (short)(u >> 16);                                               \
      fl0[i] = (short)(__float_as_uint(s0A[i] - __uint_as_float(u & 0xffff0000u)) >> 16); \
      u = __float_as_uint(s0B[i]);                                             \
      fh0[i + 4] = (short)(u >> 16);                                           \
      fl0[i + 4] = (short)(__float_as_uint(s0B[i] - __uint_as_float(u & 0xffff0000u)) >> 16); \
      u = __float_as_uint(s1A[i]);                                             \
      fh1[i] = (short)(u >> 16);                                               \
      fl1[i] = (short)(__float_as_uint(s1A[i] - __uint_as_float(u & 0xffff0000u)) >> 16); \
      u = __float_as_uint(s1B[i]);                                             \
      fh1[i + 4] = (short)(u >> 16);                                           \
      fl1[i + 4] = (short)(__float_as_uint(s1B[i] - __uint_as_float(u & 0xffff0000u)) >> 16); \
    }                                                                          \
    acc[0][0] = __builtin_amdgcn_mfma_f32_16x16x32_bf16(fh0, h0, acc[0][0], 0, 0, 0); \
    acc[0][0] = __builtin_amdgcn_mfma_f32_16x16x32_bf16(fl0, h0, acc[0][0], 0, 0, 0); \
    acc[0][0] = __builtin_amdgcn_mfma_f32_16x16x32_bf16(fh0, l0, acc[0][0], 0, 0, 0); \
    acc[0][1] = __builtin_amdgcn_mfma_f32_16x16x32_bf16(fh0, h1, acc[0][1], 0, 0, 0); \
    acc[0][1] = __builtin_amdgcn_mfma_f32_16x16x32_bf16(fl0, h1, acc[0][1], 0, 0, 0); \
    acc[0][1] = __builtin_amdgcn_mfma_f32_16x16x32_bf16(fh0, l1, acc[0][1], 0, 0, 0); \
    acc[0][2] = __builtin_amdgcn_mfma_f32_16x16x32_bf16(fh0, h2, acc[0][2], 0, 0, 0); \
    acc[0][2] = __builtin_amdgcn_mfma_f32_16x16x32_bf16(fl0, h2, acc[0][2], 0, 0, 0); \
    acc[0][2] = __builtin_amdgcn_mfma_f32_16x16x32_bf16(fh0, l2, acc[0][2], 0, 0, 0); \
    acc[0][3] = __builtin_amdgcn_mfma_f32_16x16x32_bf16(fh0, h3, acc[0][3], 0, 0, 0); \
    acc[0][3] = __builtin_amdgcn_mfma_f32_16x16x32_bf16(fl0, h3, acc[0][3], 0, 0, 0); \
    acc[0][3] = __builtin_amdgcn_mfma_f32_16x16x32_bf16(fh0, l3, acc[0][3], 0, 0, 0); \
    acc[1][0] = __builtin_amdgcn_mfma_f32_16x16x32_bf16(fh1, h0, acc[1][0], 0, 0, 0); \
    acc[1][0] = __builtin_amdgcn_mfma_f32_16x16x32_bf16(fl1, h0, acc[1][0], 0, 0, 0); \
    acc[1][0] = __builtin_amdgcn_mfma_f32_16x16x32_bf16(fh1, l0, acc[1][0], 0, 0, 0); \
    acc[1][1] = __builtin_amdgcn_mfma_f32_16x16x32_bf16(fh1, h1, acc[1][1], 0, 0, 0); \
    acc[1][1] = __builtin_amdgcn_mfma_f32_16x16x32_bf16(fl1, h1, acc[1][1], 0, 0, 0); \
    acc[1][1] = __builtin_amdgcn_mfma_f32_16x16x32_bf16(fh1, l1, acc[1][1], 0, 0, 0); \
    acc[1][2] = __builtin_amdgcn_mfma_f32_16x16x32_bf16(fh1, h2, acc[1][2], 0, 0, 0); \
    acc[1][2] = __builtin_amdgcn_mfma_f32_16x16x32_bf16(fl1, h2, acc[1][2], 0, 0, 0); \
    acc[1][2] = __builtin_amdgcn_mfma_f32_16x16x32_bf16(fh1, l2, acc[1][2], 0, 0, 0); \
    acc[1][3] = __builtin_amdgcn_mfma_f32_16x16x32_bf16(fh1, h3, acc[1][3], 0, 0, 0); \
    acc[1][3] = __builtin_amdgcn_mfma_f32_16x16x32_bf16(fl1, h3, acc[1][3], 0, 0, 0); \
    acc[1][3] = __builtin_amdgcn_mfma_f32_16x16x32_bf16(fh1, l3, acc[1][3], 0, 0, 0); \
  } while (0)

  // prologue: step 0
  LOADA_FAST(0, a0A, a0B, a1A, a1B);
  LOADB(0, b0h, b1h, b2h, b3h, b0l, b1l, b2l, b3l);

  // steps 0..13 computed in 7 unrolled pairs; prefetch 1..14
#pragma unroll
  for (int k = 0; k < 14; k += 2) {
    LOADA_FAST((k + 1) * 32, n0A, n0B, n1A, n1B);
    LOADB((k + 1) * 32, m0h, m1h, m2h, m3h, m0l, m1l, m2l, m3l);
    CONV_MFMA(a0A, a0B, a1A, a1B, b0h, b1h, b2h, b3h, b0l, b1l, b2l, b3l);
    LOADA_FAST((k + 2) * 32, a0A, a0B, a1A, a1B);
    LOADB((k + 2) * 32, b0h, b1h, b2h, b3h, b0l, b1l, b2l, b3l);
    CONV_MFMA(n0A, n0B, n1A, n1B, m0h, m1h, m2h, m3h, m0l, m1l, m2l, m3l);
  }
  // step 14 + edge prefetch 15
  LOADA_EDGE(n0A, n0B, n1A, n1B);
  LOADB(480, m0h, m1h, m2h, m3h, m0l, m1l, m2l, m3l);
  CONV_MFMA(a0A, a0B, a1A, a1B, b0h, b1h, b2h, b3h, b0l, b1l, b2l, b3l);
  // step 15
  CONV_MFMA(n0A, n0B, n1A, n1B, m0h, m1h, m2h, m3h, m0l, m1l, m2l, m3l);

#undef LOADA_FAST
#undef LOADA_EDGE
#undef LOADB
#undef CONV_MFMA

  // epilogue: C/D layout col=lane&15, row=(lane>>4)*4+reg; store fp16
#pragma unroll
  for (int mi = 0; mi < 2; mi++) {
#pragma unroll
    for (int r = 0; r < 4; r++) {
      int grow = bm + mi * 16 + ko * 4 + r;
      if (grow < NNODES) {
#pragma unroll
        for (int ni = 0; ni < 4; ni++) {
          int col = c0 + ni * 16 + fr;
          z1h[(size_t)grow * HID + col] = __float2half(acc[mi][ni][r]);
        }
      }
    }
  }
}

// ---------------- el/er for layer 1 (from fp16 z1) ----------------
__global__ __launch_bounds__(128) void attn_lr1_kernel(const __half* __restrict__ z1h,
                                                       const float* __restrict__ al,
                                                       const float* __restrict__ ar,
                                                       float* __restrict__ el,
                                                       float* __restrict__ er) {
  int n = blockIdx.x, t = threadIdx.x;
  float v = __half2float(z1h[(size_t)n * HID + t]);
  float l = v * al[t];
  float r = v * ar[t];
#pragma unroll
  for (int m = 16; m >= 1; m >>= 1) {
    l += __shfl_xor(l, m);
    r += __shfl_xor(r, m);
  }
  if ((t & 31) == 0) {
    el[n * NH + (t >> 5)] = l;
    er[n * NH + (t >> 5)] = r;
  }
}

// ---------------- CSR offsets from sorted dst ----------------
__global__ void csr_offsets_kernel(const int* __restrict__ dst, int E, int* __restrict__ off) {
  int n = blockIdx.x * blockDim.x + threadIdx.x;
  if (n > NNODES) return;
  int lo = 0, hi = E;
  while (lo < hi) {
    int mid = (lo + hi) >> 1;
    if (dst[mid] < n) lo = mid + 1; else hi = mid;
  }
  off[n] = lo;
}

// ---------------- layer-1: wave-per-node online-softmax + fp16 aggregation ----------------
__global__ __launch_bounds__(256) void gat1_agg_kernel(const __half* __restrict__ z1h,
                                                       const float* __restrict__ el,
                                                       const float* __restrict__ er,
                                                       const int* __restrict__ src,
                                                       const int* __restrict__ off,
                                                       const float* __restrict__ b1,
                                                       float* __restrict__ h1) {
  int wid = threadIdx.x >> 6, lane = threadIdx.x & 63;
  int n = blockIdx.x * 4 + wid;
  if (n >= NNODES) return;
  __shared__ float p_sh[4][64 * 4];

  int start = off[n], end = off[n + 1];
  const float4* el4 = reinterpret_cast<const float4*>(el);
  float4 er4 = reinterpret_cast<const float4*>(er)[n];
  const __half2* zp = reinterpret_cast<const __half2*>(z1h);

  int c = lane;
  int head = c >> 4;
  float2 acc = make_float2(0.f, 0.f);
  float m0 = -INFINITY, m1 = -INFINITY, m2 = -INFINITY, m3 = -INFINITY;
  float d0 = 0.f, d1 = 0.f, d2 = 0.f, d3 = 0.f;

  for (int base = start; base < end; base += 64) {
    int cnt = min(64, end - base);
    int sr = 0;
    float e0 = -INFINITY, e1 = -INFINITY, e2 = -INFINITY, e3 = -INFINITY;
    if (lane < cnt) {
      sr = src[base + lane];
      float4 x = el4[sr];
      e0 = lrelu(x.x + er4.x);
      e1 = lrelu(x.y + er4.y);
      e2 = lrelu(x.z + er4.z);
      e3 = lrelu(x.w + er4.w);
    }
    float x0 = e0, x1 = e1, x2 = e2, x3 = e3;
#pragma unroll
    for (int msk = 32; msk >= 1; msk >>= 1) {
      x0 = fmaxf(x0, __shfl_xor(x0, msk));
      x1 = fmaxf(x1, __shfl_xor(x1, msk));
      x2 = fmaxf(x2, __shfl_xor(x2, msk));
      x3 = fmaxf(x3, __shfl_xor(x3, msk));
    }
    float n0 = fmaxf(m0, x0), n1 = fmaxf(m1, x1), n2 = fmaxf(m2, x2), n3 = fmaxf(m3, x3);
    float p0 = 0.f, p1 = 0.f, p2 = 0.f, p3 = 0.f;
    if (lane < cnt) {
      p0 = __expf(e0 - n0); p1 = __expf(e1 - n1);
      p2 = __expf(e2 - n2); p3 = __expf(e3 - n3);
    }
    float s0 = p0, s1 = p1, s2 = p2, s3 = p3;
#pragma unroll
    for (int msk = 32; msk >= 1; msk >>= 1) {
      s0 += __shfl_xor(s0, msk);
      s1 += __shfl_xor(s1, msk);
      s2 += __shfl_xor(s2, msk);
      s3 += __shfl_xor(s3, msk);
    }
    float sc0 = __expf(m0 - n0), sc1 = __expf(m1 - n1);
    float sc2 = __expf(m2 - n2), sc3 = __expf(m3 - n3);
    d0 = d0 * sc0 + s0; d1 = d1 * sc1 + s1;
    d2 = d2 * sc2 + s2; d3 = d3 * sc3 + s3;
    m0 = n0; m1 = n1; m2 = n2; m3 = n3;
    float sch = sel4(sc0, sc1, sc2, sc3, head);
    acc.x *= sch;
    acc.y *= sch;
    *(float4*)&p_sh[wid][lane * 4] = make_float4(p0, p1, p2, p3);
    __builtin_amdgcn_wave_barrier();
    int i = 0;
    for (; i + 1 < cnt; i += 2) {
      int sa = __shfl(sr, i), sb = __shfl(sr, i + 1);
      float pa = p_sh[wid][i * 4 + head];
      float pb = p_sh[wid][(i + 1) * 4 + head];
      float2 va = __half22float2(zp[(size_t)sa * 64 + c]);
      float2 vb = __half22float2(zp[(size_t)sb * 64 + c]);
      acc.x = fmaf(pa, va.x, acc.x); acc.y = fmaf(pa, va.y, acc.y);
      acc.x = fmaf(pb, vb.x, acc.x); acc.y = fmaf(pb, vb.y, acc.y);
    }
    if (i < cnt) {
      int sa = __shfl(sr, i);
      float pa = p_sh[wid][i * 4 + head];
      float2 va = __half22float2(zp[(size_t)sa * 64 + c]);
      acc.x = fmaf(pa, va.x, acc.x); acc.y = fmaf(pa, va.y, acc.y);
    }
    __builtin_amdgcn_wave_barrier();
  }

  float dh = sel4(d0, d1, d2, d3, head);
  float inv = 1.f / fmaxf(dh, 1e-9f);
  float2 bias = reinterpret_cast<const float2*>(b1)[c];
  float v0 = acc.x * inv + bias.x;
  float v1 = acc.y * inv + bias.y;
  v0 = v0 > 0.f ? v0 : __expf(v0) - 1.f;
  v1 = v1 > 0.f ? v1 : __expf(v1) - 1.f;
  reinterpret_cast<float2*>(h1)[(size_t)n * 64 + c] = make_float2(v0, v1);
}

// ---------------- layer-2 projection: z2el = (z2[0..2], el2); er2 separate ----------------
__global__ __launch_bounds__(128) void proj2_kernel(const float* __restrict__ h1,
                                                    const float* __restrict__ W2,
                                                    const float* __restrict__ al2,
                                                    const float* __restrict__ ar2,
                                                    float4* __restrict__ z2el,
                                                    float* __restrict__ er2) {
  int n = blockIdx.x, t = threadIdx.x;
  float hv = h1[(size_t)n * HID + t];
  float p0 = hv * W2[t * 3 + 0];
  float p1 = hv * W2[t * 3 + 1];
  float p2 = hv * W2[t * 3 + 2];
#pragma unroll
  for (int msk = 32; msk >= 1; msk >>= 1) {
    p0 += __shfl_xor(p0, msk);
    p1 += __shfl_xor(p1, msk);
    p2 += __shfl_xor(p2, msk);
  }
  __shared__ float red[2][3];
  if ((t & 63) == 0) {
    red[t >> 6][0] = p0; red[t >> 6][1] = p1; red[t >> 6][2] = p2;
  }
  __syncthreads();
  if (t == 0) {
    float a = red[0][0] + red[1][0];
    float b = red[0][1] + red[1][1];
    float c = red[0][2] + red[1][2];
    z2el[n] = make_float4(a, b, c, a * al2[0] + b * al2[1] + c * al2[2]);
    er2[n] = a * ar2[0] + b * ar2[1] + c * ar2[2];
  }
}

// ---------------- layer-2: wave-per-node single-pass softmax + aggregation ----------------
__global__ __launch_bounds__(256) void gat2_agg_kernel(const float4* __restrict__ z2el,
                                                       const float* __restrict__ er2,
                                                       const int* __restrict__ src,
                                                       const int* __restrict__ off,
                                                       const float* __restrict__ b2,
                                                       float* __restrict__ out) {
  int wid = threadIdx.x >> 6, lane = threadIdx.x & 63;
  int n = blockIdx.x * 4 + wid;
  if (n >= NNODES) return;
  int start = off[n], end = off[n + 1];
  float ern = er2[n];
  float m_run = -INFINITY, d_run = 0.f;
  float a0 = 0.f, a1 = 0.f, a2 = 0.f;
  for (int base = start; base < end; base += 64) {
    int cnt = min(64, end - base);
    float4 z4 = make_float4(0.f, 0.f, 0.f, 0.f);
    float e = -INFINITY;
    if (lane < cnt) {
      z4 = z2el[src[base + lane]];
      e = lrelu(z4.w + ern);
    }
    float mx = e;
#pragma unroll
    for (int msk = 32; msk >= 1; msk >>= 1) mx = fmaxf(mx, __shfl_xor(mx, msk));
    float m_new = fmaxf(m_run, mx);
    float p = (lane < cnt) ? __expf(e - m_new) : 0.f;
    float sm = p;
#pragma unroll
    for (int msk = 32; msk >= 1; msk >>= 1) sm += __shfl_xor(sm, msk);
    float scale = __expf(m_run - m_new);
    d_run = d_run * scale + sm;
    a0 = a0 * scale + p * z4.x;
    a1 = a1 * scale + p * z4.y;
    a2 = a2 * scale + p * z4.z;
    m_run = m_new;
  }
#pragma unroll
  for (int msk = 32; msk >= 1; msk >>= 1) {
    a0 += __shfl_xor(a0, msk);
    a1 += __shfl_xor(a1, msk);
    a2 += __shfl_xor(a2, msk);
  }
  if (lane == 0) {
    float inv = 1.f / fmaxf(d_run, 1e-9f);
    out[n * 3 + 0] = a0 * inv + b2[0];
    out[n * 3 + 1] = a1 * inv + b2[1];
    out[n * 3 + 2] = a2 * inv + b2[2];
  }
}

extern "C" void kernel_launch(void* const* d_in, const int* in_sizes, int n_in,
                              void* d_out, int out_size, void* d_ws, size_t ws_size,
                              hipStream_t stream) {
  const float* features = (const float*)d_in[0];
  const int* src = (const int*)d_in[1];
  const int* dst = (const int*)d_in[2];
  const float* W1 = (const float*)d_in[3];
  const float* al1 = (const float*)d_in[4];
  const float* ar1 = (const float*)d_in[5];
  const float* b1 = (const float*)d_in[6];
  const float* W2 = (const float*)d_in[7];
  const float* al2 = (const float*)d_in[8];
  const float* ar2 = (const float*)d_in[9];
  const float* b2 = (const float*)d_in[10];
  float* out = (float*)d_out;
  int E = in_sizes[1];

  char* ws = (char*)d_ws;
  size_t o = 0;
  __half* z1h = (__half*)(ws + o); o += (size_t)NNODES * HID * 2;
  float* h1 = (float*)(ws + o);    o += (size_t)NNODES * HID * 4;
  float* el1 = (float*)(ws + o);   o += (size_t)NNODES * NH * 4;
  float* er1 = (float*)(ws + o);   o += (size_t)NNODES * NH * 4;
  float4* z2el = (float4*)(ws + o); o += (size_t)NNODES * 16;
  float* er2 = (float*)(ws + o);   o += (size_t)NNODES * 4;
  short* BhT = (short*)(ws + o);   o += (size_t)HID * KP * 2;
  short* BlT = (short*)(ws + o);   o += (size_t)HID * KP * 2;
  int* off = (int*)(ws + o);       o += (size_t)(NNODES + 1) * 4;

  convert_w1_kernel<<<256, 256, 0, stream>>>(W1, BhT, BlT);
  gemm1_mfma_kernel<<<782 * 2, 256, 0, stream>>>(features, BhT, BlT, z1h);
  attn_lr1_kernel<<<NNODES, 128, 0, stream>>>(z1h, al1, ar1, el1, er1);
  csr_offsets_kernel<<<(NNODES + 1 + 255) / 256, 256, 0, stream>>>(dst, E, off);
  gat1_agg_kernel<<<(NNODES + 3) / 4, 256, 0, stream>>>(z1h, el1, er1, src, off, b1, h1);
  proj2_kernel<<<NNODES, 128, 0, stream>>>(h1, W2, al2, ar2, z2el, er2);
  gat2_agg_kernel<<<(NNODES + 3) / 4, 256, 0, stream>>>(z2el, er2, src, off, b2, out);
}

// Round 7
// 297.308 us; speedup vs baseline: 1.2811x; 1.2811x over previous
//
#include <hip/hip_runtime.h>
#include <hip/hip_fp16.h>
#include <math.h>

#define NNODES 100000
#define NEG_SLOPE 0.2f
#define FIN 500
#define KP 512     // padded K
#define HID 128    // heads*hidden
#define NH 4
#define BM 64      // rows per block

typedef __attribute__((ext_vector_type(8))) short short8v;
typedef __attribute__((ext_vector_type(4))) float f32x4;

__device__ __forceinline__ float lrelu(float x) { return x > 0.f ? x : NEG_SLOPE * x; }

__device__ __forceinline__ float sel4(float a0, float a1, float a2, float a3, int h) {
  float r = a0;
  r = (h == 1) ? a1 : r;
  r = (h == 2) ? a2 : r;
  r = (h == 3) ? a3 : r;
  return r;
}

__device__ __forceinline__ unsigned short f32_to_bf16_rn(float f) {
  unsigned u = __float_as_uint(f);
  unsigned r = u + 0x7fffu + ((u >> 16) & 1u);
  return (unsigned short)(r >> 16);
}
__device__ __forceinline__ float bf16_to_f32(unsigned short h) {
  return __uint_as_float(((unsigned)h) << 16);
}

// ---------------- W1 -> transposed bf16 hi/lo [128][512] ----------------
__global__ __launch_bounds__(256) void convert_w1_kernel(const float* __restrict__ W1,
                                                         short* __restrict__ BhT,
                                                         short* __restrict__ BlT) {
  int idx = blockIdx.x * 256 + threadIdx.x;  // 65536
  int n = idx >> 9, k = idx & 511;
  float v = (k < FIN) ? W1[k * HID + n] : 0.f;
  unsigned short hb = f32_to_bf16_rn(v);
  float lo = v - bf16_to_f32(hb);
  BhT[n * KP + k] = (short)hb;
  BlT[n * KP + k] = (short)f32_to_bf16_rn(lo);
}

// ---------------- GEMM1: BM=64 tile, LDS-staged A(conv)+B(copy), fused el/er ----------------
// 4 waves, each 16 rows x 128 cols. LDS 24 KB single-buffered, 2 barriers/step.
// LDS layouts chunked [kslot][row][16B] -> conflict-free 16B/lane reads.
__global__ __launch_bounds__(256, 4) void gemm1_mfma_kernel(const float* __restrict__ A,
                                                            const short* __restrict__ BhT,
                                                            const short* __restrict__ BlT,
                                                            const float* __restrict__ al,
                                                            const float* __restrict__ ar,
                                                            __half* __restrict__ z1h,
                                                            float* __restrict__ el,
                                                            float* __restrict__ er) {
  __shared__ __align__(16) short AhL[4 * 64 * 8];   // 4 KB
  __shared__ __align__(16) short AlL[4 * 64 * 8];   // 4 KB
  __shared__ __align__(16) short BhL[4 * 128 * 8];  // 8 KB
  __shared__ __align__(16) short BlL[4 * 128 * 8];  // 8 KB

  const int t = threadIdx.x;
  const int w = t >> 6, lane = t & 63;
  const int fr = lane & 15, ko = lane >> 4;
  const int bm = blockIdx.x * BM;

  // A staging map: thread t -> row=t>>2 (0..63), slot=t&3 (8 f32 = 32B)
  const int srow = t >> 2, sslot = t & 3;
  const int arow = min(bm + srow, NNODES - 1);
  const float* pA = A + (size_t)arow * FIN + sslot * 8;
  const int aoff = (sslot * 64 + srow) * 8;  // shorts

  // B staging map: units u=t, u+256; u -> slot=u>>7, col=u&127 (16B each)
  const int bslot0 = t >> 7, bcol0 = t & 127;
  const int bslot1 = bslot0 + 2;
  const short* pBh0 = BhT + (size_t)bcol0 * KP + bslot0 * 8;
  const short* pBh1 = BhT + (size_t)bcol0 * KP + bslot1 * 8;
  const short* pBl0 = BlT + (size_t)bcol0 * KP + bslot0 * 8;
  const short* pBl1 = BlT + (size_t)bcol0 * KP + bslot1 * 8;
  const int boff0 = (bslot0 * 128 + bcol0) * 8;
  const int boff1 = (bslot1 * 128 + bcol0) * 8;

  f32x4 acc[8];
#pragma unroll
  for (int i = 0; i < 8; i++) acc[i] = (f32x4){0.f, 0.f, 0.f, 0.f};

  // staging registers (1-deep lookahead)
  f32x4 a0, a1;
  short8v sbh0, sbh1, sbl0, sbl1;

#define LOADA_FAST(K0)                       \
  do {                                       \
    a0 = *(const f32x4*)(pA + (K0));         \
    a1 = *(const f32x4*)(pA + (K0) + 4);     \
  } while (0)

#define LOADA_EDGE()                                              \
  do {                                                            \
    _Pragma("unroll")                                             \
    for (int i = 0; i < 4; i++) {                                 \
      int kk = 480 + sslot * 8 + i;                               \
      a0[i] = (kk < FIN) ? pA[480 + i] : 0.f;                     \
      a1[i] = (kk + 4 < FIN) ? pA[484 + i] : 0.f;                 \
    }                                                             \
  } while (0)

#define LOADB(K0)                                \
  do {                                           \
    sbh0 = *(const short8v*)(pBh0 + (K0));       \
    sbh1 = *(const short8v*)(pBh1 + (K0));       \
    sbl0 = *(const short8v*)(pBl0 + (K0));       \
    sbl1 = *(const short8v*)(pBl1 + (K0));       \
  } while (0)

#define WRITE_STAGE()                                                              \
  do {                                                                             \
    short8v hv, lv;                                                                \
    _Pragma("unroll")                                                              \
    for (int i = 0; i < 4; i++) {                                                  \
      unsigned u = __float_as_uint(a0[i]);                                         \
      hv[i] = (short)(u >> 16);                                                    \
      lv[i] = (short)(__float_as_uint(a0[i] - __uint_as_float(u & 0xffff0000u)) >> 16); \
      u = __float_as_uint(a1[i]);                                                  \
      hv[i + 4] = (short)(u >> 16);                                                \
      lv[i + 4] = (short)(__float_as_uint(a1[i] - __uint_as_float(u & 0xffff0000u)) >> 16); \
    }                                                                              \
    *(short8v*)&AhL[aoff] = hv;                                                    \
    *(short8v*)&AlL[aoff] = lv;                                                    \
    *(short8v*)&BhL[boff0] = sbh0;                                                 \
    *(short8v*)&BhL[boff1] = sbh1;                                                 \
    *(short8v*)&BlL[boff0] = sbl0;                                                 \
    *(short8v*)&BlL[boff1] = sbl1;                                                 \
  } while (0)

  const int afr = (ko * 64 + w * 16 + fr) * 8;

  // prologue
  LOADA_FAST(0);
  LOADB(0);

#pragma unroll
  for (int k = 0; k < 16; k++) {
    WRITE_STAGE();
    __syncthreads();
    if (k < 15) {
      if (k + 1 == 15) LOADA_EDGE(); else LOADA_FAST((k + 1) * 32);
      LOADB((k + 1) * 32);
    }
    // compute step k from LDS
    short8v ah = *(short8v*)&AhL[afr];
    short8v am = *(short8v*)&AlL[afr];
#pragma unroll
    for (int ni = 0; ni < 8; ni++) {
      const int bfr = (ko * 128 + ni * 16 + fr) * 8;
      short8v bh = *(short8v*)&BhL[bfr];
      short8v bl = *(short8v*)&BlL[bfr];
      acc[ni] = __builtin_amdgcn_mfma_f32_16x16x32_bf16(ah, bh, acc[ni], 0, 0, 0);
      acc[ni] = __builtin_amdgcn_mfma_f32_16x16x32_bf16(am, bh, acc[ni], 0, 0, 0);
      acc[ni] = __builtin_amdgcn_mfma_f32_16x16x32_bf16(ah, bl, acc[ni], 0, 0, 0);
    }
    __syncthreads();
  }

#undef LOADA_FAST
#undef LOADA_EDGE
#undef LOADB
#undef WRITE_STAGE

  // epilogue: z1h stores + fused el/er (wave owns full rows)
  float alv[8], arv[8];
#pragma unroll
  for (int ni = 0; ni < 8; ni++) {
    alv[ni] = al[ni * 16 + fr];
    arv[ni] = ar[ni * 16 + fr];
  }
#pragma unroll
  for (int r = 0; r < 4; r++) {
    int grow = bm + w * 16 + ko * 4 + r;
    bool ok = grow < NNODES;
    if (ok) {
#pragma unroll
      for (int ni = 0; ni < 8; ni++)
        z1h[(size_t)grow * HID + ni * 16 + fr] = __float2half(acc[ni][r]);
    }
#pragma unroll
    for (int h = 0; h < 4; h++) {
      float cl = acc[2 * h][r] * alv[2 * h] + acc[2 * h + 1][r] * alv[2 * h + 1];
      float cr = acc[2 * h][r] * arv[2 * h] + acc[2 * h + 1][r] * arv[2 * h + 1];
#pragma unroll
      for (int m = 1; m <= 8; m <<= 1) {
        cl += __shfl_xor(cl, m);
        cr += __shfl_xor(cr, m);
      }
      if (fr == 0 && ok) {
        el[grow * NH + h] = cl;
        er[grow * NH + h] = cr;
      }
    }
  }
}

// ---------------- CSR offsets from sorted dst ----------------
__global__ void csr_offsets_kernel(const int* __restrict__ dst, int E, int* __restrict__ off) {
  int n = blockIdx.x * blockDim.x + threadIdx.x;
  if (n > NNODES) return;
  int lo = 0, hi = E;
  while (lo < hi) {
    int mid = (lo + hi) >> 1;
    if (dst[mid] < n) lo = mid + 1; else hi = mid;
  }
  off[n] = lo;
}

// ---------------- layer-1: wave-per-node online-softmax + fp16 aggregation ----------------
__global__ __launch_bounds__(256) void gat1_agg_kernel(const __half* __restrict__ z1h,
                                                       const float* __restrict__ el,
                                                       const float* __restrict__ er,
                                                       const int* __restrict__ src,
                                                       const int* __restrict__ off,
                                                       const float* __restrict__ b1,
                                                       float* __restrict__ h1) {
  int wid = threadIdx.x >> 6, lane = threadIdx.x & 63;
  int n = blockIdx.x * 4 + wid;
  if (n >= NNODES) return;
  __shared__ float p_sh[4][64 * 4];

  int start = off[n], end = off[n + 1];
  const float4* el4 = reinterpret_cast<const float4*>(el);
  float4 er4 = reinterpret_cast<const float4*>(er)[n];
  const __half2* zp = reinterpret_cast<const __half2*>(z1h);

  int c = lane;
  int head = c >> 4;
  float2 acc = make_float2(0.f, 0.f);
  float m0 = -INFINITY, m1 = -INFINITY, m2 = -INFINITY, m3 = -INFINITY;
  float d0 = 0.f, d1 = 0.f, d2 = 0.f, d3 = 0.f;

  for (int base = start; base < end; base += 64) {
    int cnt = min(64, end - base);
    int sr = 0;
    float e0 = -INFINITY, e1 = -INFINITY, e2 = -INFINITY, e3 = -INFINITY;
    if (lane < cnt) {
      sr = src[base + lane];
      float4 x = el4[sr];
      e0 = lrelu(x.x + er4.x);
      e1 = lrelu(x.y + er4.y);
      e2 = lrelu(x.z + er4.z);
      e3 = lrelu(x.w + er4.w);
    }
    float x0 = e0, x1 = e1, x2 = e2, x3 = e3;
#pragma unroll
    for (int msk = 32; msk >= 1; msk >>= 1) {
      x0 = fmaxf(x0, __shfl_xor(x0, msk));
      x1 = fmaxf(x1, __shfl_xor(x1, msk));
      x2 = fmaxf(x2, __shfl_xor(x2, msk));
      x3 = fmaxf(x3, __shfl_xor(x3, msk));
    }
    float n0 = fmaxf(m0, x0), n1 = fmaxf(m1, x1), n2 = fmaxf(m2, x2), n3 = fmaxf(m3, x3);
    float p0 = 0.f, p1 = 0.f, p2 = 0.f, p3 = 0.f;
    if (lane < cnt) {
      p0 = __expf(e0 - n0); p1 = __expf(e1 - n1);
      p2 = __expf(e2 - n2); p3 = __expf(e3 - n3);
    }
    float s0 = p0, s1 = p1, s2 = p2, s3 = p3;
#pragma unroll
    for (int msk = 32; msk >= 1; msk >>= 1) {
      s0 += __shfl_xor(s0, msk);
      s1 += __shfl_xor(s1, msk);
      s2 += __shfl_xor(s2, msk);
      s3 += __shfl_xor(s3, msk);
    }
    float sc0 = __expf(m0 - n0), sc1 = __expf(m1 - n1);
    float sc2 = __expf(m2 - n2), sc3 = __expf(m3 - n3);
    d0 = d0 * sc0 + s0; d1 = d1 * sc1 + s1;
    d2 = d2 * sc2 + s2; d3 = d3 * sc3 + s3;
    m0 = n0; m1 = n1; m2 = n2; m3 = n3;
    float sch = sel4(sc0, sc1, sc2, sc3, head);
    acc.x *= sch;
    acc.y *= sch;
    *(float4*)&p_sh[wid][lane * 4] = make_float4(p0, p1, p2, p3);
    __builtin_amdgcn_wave_barrier();
    int i = 0;
    for (; i + 1 < cnt; i += 2) {
      int sa = __shfl(sr, i), sb = __shfl(sr, i + 1);
      float pa = p_sh[wid][i * 4 + head];
      float pb = p_sh[wid][(i + 1) * 4 + head];
      float2 va = __half22float2(zp[(size_t)sa * 64 + c]);
      float2 vb = __half22float2(zp[(size_t)sb * 64 + c]);
      acc.x = fmaf(pa, va.x, acc.x); acc.y = fmaf(pa, va.y, acc.y);
      acc.x = fmaf(pb, vb.x, acc.x); acc.y = fmaf(pb, vb.y, acc.y);
    }
    if (i < cnt) {
      int sa = __shfl(sr, i);
      float pa = p_sh[wid][i * 4 + head];
      float2 va = __half22float2(zp[(size_t)sa * 64 + c]);
      acc.x = fmaf(pa, va.x, acc.x); acc.y = fmaf(pa, va.y, acc.y);
    }
    __builtin_amdgcn_wave_barrier();
  }

  float dh = sel4(d0, d1, d2, d3, head);
  float inv = 1.f / fmaxf(dh, 1e-9f);
  float2 bias = reinterpret_cast<const float2*>(b1)[c];
  float v0 = acc.x * inv + bias.x;
  float v1 = acc.y * inv + bias.y;
  v0 = v0 > 0.f ? v0 : __expf(v0) - 1.f;
  v1 = v1 > 0.f ? v1 : __expf(v1) - 1.f;
  reinterpret_cast<float2*>(h1)[(size_t)n * 64 + c] = make_float2(v0, v1);
}

// ---------------- layer-2 projection: wave-per-node ----------------
__global__ __launch_bounds__(256) void proj2_kernel(const float* __restrict__ h1,
                                                    const float* __restrict__ W2,
                                                    const float* __restrict__ al2,
                                                    const float* __restrict__ ar2,
                                                    float4* __restrict__ z2el,
                                                    float* __restrict__ er2) {
  int wid = threadIdx.x >> 6, lane = threadIdx.x & 63;
  int n = blockIdx.x * 4 + wid;
  if (n >= NNODES) return;
  float2 hv = reinterpret_cast<const float2*>(h1)[(size_t)n * 64 + lane];
  int c0 = 2 * lane, c1 = 2 * lane + 1;
  float p0 = hv.x * W2[c0 * 3 + 0] + hv.y * W2[c1 * 3 + 0];
  float p1 = hv.x * W2[c0 * 3 + 1] + hv.y * W2[c1 * 3 + 1];
  float p2 = hv.x * W2[c0 * 3 + 2] + hv.y * W2[c1 * 3 + 2];
#pragma unroll
  for (int msk = 32; msk >= 1; msk >>= 1) {
    p0 += __shfl_xor(p0, msk);
    p1 += __shfl_xor(p1, msk);
    p2 += __shfl_xor(p2, msk);
  }
  if (lane == 0) {
    z2el[n] = make_float4(p0, p1, p2, p0 * al2[0] + p1 * al2[1] + p2 * al2[2]);
    er2[n] = p0 * ar2[0] + p1 * ar2[1] + p2 * ar2[2];
  }
}

// ---------------- layer-2: wave-per-node single-pass softmax + aggregation ----------------
__global__ __launch_bounds__(256) void gat2_agg_kernel(const float4* __restrict__ z2el,
                                                       const float* __restrict__ er2,
                                                       const int* __restrict__ src,
                                                       const int* __restrict__ off,
                                                       const float* __restrict__ b2,
                                                       float* __restrict__ out) {
  int wid = threadIdx.x >> 6, lane = threadIdx.x & 63;
  int n = blockIdx.x * 4 + wid;
  if (n >= NNODES) return;
  int start = off[n], end = off[n + 1];
  float ern = er2[n];
  float m_run = -INFINITY, d_run = 0.f;
  float a0 = 0.f, a1 = 0.f, a2 = 0.f;
  for (int base = start; base < end; base += 64) {
    int cnt = min(64, end - base);
    float4 z4 = make_float4(0.f, 0.f, 0.f, 0.f);
    float e = -INFINITY;
    if (lane < cnt) {
      z4 = z2el[src[base + lane]];
      e = lrelu(z4.w + ern);
    }
    float mx = e;
#pragma unroll
    for (int msk = 32; msk >= 1; msk >>= 1) mx = fmaxf(mx, __shfl_xor(mx, msk));
    float m_new = fmaxf(m_run, mx);
    float p = (lane < cnt) ? __expf(e - m_new) : 0.f;
    float sm = p;
#pragma unroll
    for (int msk = 32; msk >= 1; msk >>= 1) sm += __shfl_xor(sm, msk);
    float scale = __expf(m_run - m_new);
    d_run = d_run * scale + sm;
    a0 = a0 * scale + p * z4.x;
    a1 = a1 * scale + p * z4.y;
    a2 = a2 * scale + p * z4.z;
    m_run = m_new;
  }
#pragma unroll
  for (int msk = 32; msk >= 1; msk >>= 1) {
    a0 += __shfl_xor(a0, msk);
    a1 += __shfl_xor(a1, msk);
    a2 += __shfl_xor(a2, msk);
  }
  if (lane == 0) {
    float inv = 1.f / fmaxf(d_run, 1e-9f);
    out[n * 3 + 0] = a0 * inv + b2[0];
    out[n * 3 + 1] = a1 * inv + b2[1];
    out[n * 3 + 2] = a2 * inv + b2[2];
  }
}

extern "C" void kernel_launch(void* const* d_in, const int* in_sizes, int n_in,
                              void* d_out, int out_size, void* d_ws, size_t ws_size,
                              hipStream_t stream) {
  const float* features = (const float*)d_in[0];
  const int* src = (const int*)d_in[1];
  const int* dst = (const int*)d_in[2];
  const float* W1 = (const float*)d_in[3];
  const float* al1 = (const float*)d_in[4];
  const float* ar1 = (const float*)d_in[5];
  const float* b1 = (const float*)d_in[6];
  const float* W2 = (const float*)d_in[7];
  const float* al2 = (const float*)d_in[8];
  const float* ar2 = (const float*)d_in[9];
  const float* b2 = (const float*)d_in[10];
  float* out = (float*)d_out;
  int E = in_sizes[1];

  char* ws = (char*)d_ws;
  size_t o = 0;
  __half* z1h = (__half*)(ws + o); o += (size_t)NNODES * HID * 2;
  float* h1 = (float*)(ws + o);    o += (size_t)NNODES * HID * 4;
  float* el1 = (float*)(ws + o);   o += (size_t)NNODES * NH * 4;
  float* er1 = (float*)(ws + o);   o += (size_t)NNODES * NH * 4;
  float4* z2el = (float4*)(ws + o); o += (size_t)NNODES * 16;
  float* er2 = (float*)(ws + o);   o += (size_t)NNODES * 4;
  short* BhT = (short*)(ws + o);   o += (size_t)HID * KP * 2;
  short* BlT = (short*)(ws + o);   o += (size_t)HID * KP * 2;
  int* off = (int*)(ws + o);       o += (size_t)(NNODES + 1) * 4;

  convert_w1_kernel<<<256, 256, 0, stream>>>(W1, BhT, BlT);
  gemm1_mfma_kernel<<<(NNODES + BM - 1) / BM, 256, 0, stream>>>(features, BhT, BlT, al1, ar1,
                                                                z1h, el1, er1);
  csr_offsets_kernel<<<(NNODES + 1 + 255) / 256, 256, 0, stream>>>(dst, E, off);
  gat1_agg_kernel<<<(NNODES + 3) / 4, 256, 0, stream>>>(z1h, el1, er1, src, off, b1, h1);
  proj2_kernel<<<(NNODES + 3) / 4, 256, 0, stream>>>(h1, W2, al2, ar2, z2el, er2);
  gat2_agg_kernel<<<(NNODES + 3) / 4, 256, 0, stream>>>(z2el, er2, src, off, b2, out);
}

// Round 8
// 270.677 us; speedup vs baseline: 1.4072x; 1.0984x over previous
//
#include <hip/hip_runtime.h>
#include <hip/hip_fp16.h>
#include <math.h>

#define NNODES 100000
#define NEG_SLOPE 0.2f
#define FIN 500
#define KP 512     // padded K
#define HID 128    // heads*hidden
#define NH 4
#define BM 128     // rows per block

typedef __attribute__((ext_vector_type(8))) short short8v;
typedef __attribute__((ext_vector_type(4))) float f32x4;

__device__ __forceinline__ float lrelu(float x) { return x > 0.f ? x : NEG_SLOPE * x; }

__device__ __forceinline__ float sel4(float a0, float a1, float a2, float a3, int h) {
  float r = a0;
  r = (h == 1) ? a1 : r;
  r = (h == 2) ? a2 : r;
  r = (h == 3) ? a3 : r;
  return r;
}

__device__ __forceinline__ unsigned short f32_to_bf16_rn(float f) {
  unsigned u = __float_as_uint(f);
  unsigned r = u + 0x7fffu + ((u >> 16) & 1u);
  return (unsigned short)(r >> 16);
}
__device__ __forceinline__ float bf16_to_f32(unsigned short h) {
  return __uint_as_float(((unsigned)h) << 16);
}

// swizzled LDS offset (shorts): row stride 32 shorts (64B), 16B slots XOR'd by row
// measured conflict-free on reads AND writes (r2/r4/r5: SQ_LDS_BANK_CONFLICT = 0)
__device__ __forceinline__ int lds_off(int row, int slot8) {
  return row * 32 + ((slot8 ^ ((row >> 1) & 3)) << 3);
}

// ---------------- W1 -> transposed bf16 hi/lo [128][512] ----------------
__global__ __launch_bounds__(256) void convert_w1_kernel(const float* __restrict__ W1,
                                                         short* __restrict__ BhT,
                                                         short* __restrict__ BlT) {
  int idx = blockIdx.x * 256 + threadIdx.x;  // 65536
  int n = idx >> 9, k = idx & 511;
  float v = (k < FIN) ? W1[k * HID + n] : 0.f;
  unsigned short hb = f32_to_bf16_rn(v);
  float lo = v - bf16_to_f32(hb);
  BhT[n * KP + k] = (short)hb;
  BlT[n * KP + k] = (short)f32_to_bf16_rn(lo);
}

// ---------------- GEMM1: BM=128, swizzled LDS, fused el/er ----------------
// 4 waves, each 32 rows x 128 cols (acc[2][8]). LDS 32 KB single-buffered.
__global__ __launch_bounds__(256, 3) void gemm1_mfma_kernel(const float* __restrict__ A,
                                                            const short* __restrict__ BhT,
                                                            const short* __restrict__ BlT,
                                                            const float* __restrict__ al,
                                                            const float* __restrict__ ar,
                                                            __half* __restrict__ z1h,
                                                            float* __restrict__ el,
                                                            float* __restrict__ er) {
  __shared__ __align__(16) short AhL[128 * 32];  // 8 KB
  __shared__ __align__(16) short AlL[128 * 32];  // 8 KB
  __shared__ __align__(16) short BhL[128 * 32];  // 8 KB
  __shared__ __align__(16) short BlL[128 * 32];  // 8 KB

  const int t = threadIdx.x;
  const int w = t >> 6, lane = t & 63;
  const int fr = lane & 15, ko = lane >> 4;
  const int bm = blockIdx.x * BM;

  // A staging: thread t -> rows srow0, srow0+64; slot sslot (8 f32 = 32B each)
  const int srow0 = t >> 2, sslot = t & 3;
  const int arow0 = min(bm + srow0, NNODES - 1);
  const int arow1 = min(bm + srow0 + 64, NNODES - 1);
  const float* pA0 = A + (size_t)arow0 * FIN + sslot * 8;
  const float* pA1 = A + (size_t)arow1 * FIN + sslot * 8;
  const int aoff0 = lds_off(srow0, sslot);
  const int aoff1 = lds_off(srow0 + 64, sslot);

  // B staging: units u = t, t+256; u -> col=u&127, slot=u>>7
  const int bcol = t & 127, bslot0 = t >> 7, bslot1 = bslot0 + 2;
  const short* pBh0 = BhT + (size_t)bcol * KP + bslot0 * 8;
  const short* pBh1 = BhT + (size_t)bcol * KP + bslot1 * 8;
  const short* pBl0 = BlT + (size_t)bcol * KP + bslot0 * 8;
  const short* pBl1 = BlT + (size_t)bcol * KP + bslot1 * 8;
  const int boff0 = lds_off(bcol, bslot0);
  const int boff1 = lds_off(bcol, bslot1);

  f32x4 acc[2][8];
#pragma unroll
  for (int i = 0; i < 2; i++)
#pragma unroll
    for (int j = 0; j < 8; j++) acc[i][j] = (f32x4){0.f, 0.f, 0.f, 0.f};

  // staging registers (1-deep lookahead)
  f32x4 a00, a01, a10, a11;
  short8v sbh0, sbh1, sbl0, sbl1;

#define LOADA_FAST(K0)                        \
  do {                                        \
    a00 = *(const f32x4*)(pA0 + (K0));        \
    a01 = *(const f32x4*)(pA0 + (K0) + 4);    \
    a10 = *(const f32x4*)(pA1 + (K0));        \
    a11 = *(const f32x4*)(pA1 + (K0) + 4);    \
  } while (0)

#define LOADA_EDGE()                                              \
  do {                                                            \
    _Pragma("unroll")                                             \
    for (int i = 0; i < 4; i++) {                                 \
      int kk = 480 + sslot * 8 + i;                               \
      a00[i] = (kk < FIN) ? pA0[480 + i] : 0.f;                   \
      a10[i] = (kk < FIN) ? pA1[480 + i] : 0.f;                   \
      a01[i] = (kk + 4 < FIN) ? pA0[484 + i] : 0.f;               \
      a11[i] = (kk + 4 < FIN) ? pA1[484 + i] : 0.f;               \
    }                                                             \
  } while (0)

#define LOADB(K0)                                \
  do {                                           \
    sbh0 = *(const short8v*)(pBh0 + (K0));       \
    sbh1 = *(const short8v*)(pBh1 + (K0));       \
    sbl0 = *(const short8v*)(pBl0 + (K0));       \
    sbl1 = *(const short8v*)(pBl1 + (K0));       \
  } while (0)

#define WRITE_STAGE()                                                              \
  do {                                                                             \
    short8v hv0, lv0, hv1, lv1;                                                    \
    _Pragma("unroll")                                                              \
    for (int i = 0; i < 4; i++) {                                                  \
      unsigned u = __float_as_uint(a00[i]);                                        \
      hv0[i] = (short)(u >> 16);                                                   \
      lv0[i] = (short)(__float_as_uint(a00[i] - __uint_as_float(u & 0xffff0000u)) >> 16); \
      u = __float_as_uint(a01[i]);                                                 \
      hv0[i + 4] = (short)(u >> 16);                                               \
      lv0[i + 4] = (short)(__float_as_uint(a01[i] - __uint_as_float(u & 0xffff0000u)) >> 16); \
      u = __float_as_uint(a10[i]);                                                 \
      hv1[i] = (short)(u >> 16);                                                   \
      lv1[i] = (short)(__float_as_uint(a10[i] - __uint_as_float(u & 0xffff0000u)) >> 16); \
      u = __float_as_uint(a11[i]);                                                 \
      hv1[i + 4] = (short)(u >> 16);                                               \
      lv1[i + 4] = (short)(__float_as_uint(a11[i] - __uint_as_float(u & 0xffff0000u)) >> 16); \
    }                                                                              \
    *(short8v*)&AhL[aoff0] = hv0;                                                  \
    *(short8v*)&AlL[aoff0] = lv0;                                                  \
    *(short8v*)&AhL[aoff1] = hv1;                                                  \
    *(short8v*)&AlL[aoff1] = lv1;                                                  \
    *(short8v*)&BhL[boff0] = sbh0;                                                 \
    *(short8v*)&BhL[boff1] = sbh1;                                                 \
    *(short8v*)&BlL[boff0] = sbl0;                                                 \
    *(short8v*)&BlL[boff1] = sbl1;                                                 \
  } while (0)

  const int afr0 = lds_off(w * 32 + fr, ko);
  const int afr1 = lds_off(w * 32 + 16 + fr, ko);

  // prologue
  LOADA_FAST(0);
  LOADB(0);

#pragma unroll
  for (int k = 0; k < 16; k++) {
    WRITE_STAGE();
    __syncthreads();
    if (k < 15) {
      if (k + 1 == 15) LOADA_EDGE(); else LOADA_FAST((k + 1) * 32);
      LOADB((k + 1) * 32);
    }
    short8v ah0 = *(short8v*)&AhL[afr0];
    short8v am0 = *(short8v*)&AlL[afr0];
    short8v ah1 = *(short8v*)&AhL[afr1];
    short8v am1 = *(short8v*)&AlL[afr1];
#pragma unroll
    for (int ni = 0; ni < 8; ni++) {
      const int bfr = lds_off(ni * 16 + fr, ko);
      short8v bh = *(short8v*)&BhL[bfr];
      short8v bl = *(short8v*)&BlL[bfr];
      acc[0][ni] = __builtin_amdgcn_mfma_f32_16x16x32_bf16(ah0, bh, acc[0][ni], 0, 0, 0);
      acc[0][ni] = __builtin_amdgcn_mfma_f32_16x16x32_bf16(am0, bh, acc[0][ni], 0, 0, 0);
      acc[0][ni] = __builtin_amdgcn_mfma_f32_16x16x32_bf16(ah0, bl, acc[0][ni], 0, 0, 0);
      acc[1][ni] = __builtin_amdgcn_mfma_f32_16x16x32_bf16(ah1, bh, acc[1][ni], 0, 0, 0);
      acc[1][ni] = __builtin_amdgcn_mfma_f32_16x16x32_bf16(am1, bh, acc[1][ni], 0, 0, 0);
      acc[1][ni] = __builtin_amdgcn_mfma_f32_16x16x32_bf16(ah1, bl, acc[1][ni], 0, 0, 0);
    }
    __syncthreads();
  }

#undef LOADA_FAST
#undef LOADA_EDGE
#undef LOADB
#undef WRITE_STAGE

  // epilogue: z1h stores + fused el/er (wave owns rows w*32 .. w*32+31)
  float alv[8], arv[8];
#pragma unroll
  for (int ni = 0; ni < 8; ni++) {
    alv[ni] = al[ni * 16 + fr];
    arv[ni] = ar[ni * 16 + fr];
  }
#pragma unroll
  for (int mi = 0; mi < 2; mi++) {
#pragma unroll
    for (int r = 0; r < 4; r++) {
      int grow = bm + w * 32 + mi * 16 + ko * 4 + r;
      bool ok = grow < NNODES;
      if (ok) {
#pragma unroll
        for (int ni = 0; ni < 8; ni++)
          z1h[(size_t)grow * HID + ni * 16 + fr] = __float2half(acc[mi][ni][r]);
      }
#pragma unroll
      for (int h = 0; h < 4; h++) {
        float cl = acc[mi][2 * h][r] * alv[2 * h] + acc[mi][2 * h + 1][r] * alv[2 * h + 1];
        float cr = acc[mi][2 * h][r] * arv[2 * h] + acc[mi][2 * h + 1][r] * arv[2 * h + 1];
#pragma unroll
        for (int m = 1; m <= 8; m <<= 1) {
          cl += __shfl_xor(cl, m);
          cr += __shfl_xor(cr, m);
        }
        if (fr == 0 && ok) {
          el[grow * NH + h] = cl;
          er[grow * NH + h] = cr;
        }
      }
    }
  }
}

// ---------------- CSR offsets from sorted dst ----------------
__global__ void csr_offsets_kernel(const int* __restrict__ dst, int E, int* __restrict__ off) {
  int n = blockIdx.x * blockDim.x + threadIdx.x;
  if (n > NNODES) return;
  int lo = 0, hi = E;
  while (lo < hi) {
    int mid = (lo + hi) >> 1;
    if (dst[mid] < n) lo = mid + 1; else hi = mid;
  }
  off[n] = lo;
}

// ---------------- layer-1: wave-per-node online-softmax + fp16 aggregation ----------------
__global__ __launch_bounds__(256) void gat1_agg_kernel(const __half* __restrict__ z1h,
                                                       const float* __restrict__ el,
                                                       const float* __restrict__ er,
                                                       const int* __restrict__ src,
                                                       const int* __restrict__ off,
                                                       const float* __restrict__ b1,
                                                       float* __restrict__ h1) {
  int wid = threadIdx.x >> 6, lane = threadIdx.x & 63;
  int n = blockIdx.x * 4 + wid;
  if (n >= NNODES) return;
  __shared__ float p_sh[4][64 * 4];

  int start = off[n], end = off[n + 1];
  const float4* el4 = reinterpret_cast<const float4*>(el);
  float4 er4 = reinterpret_cast<const float4*>(er)[n];
  const __half2* zp = reinterpret_cast<const __half2*>(z1h);

  int c = lane;
  int head = c >> 4;
  float2 acc = make_float2(0.f, 0.f);
  float m0 = -INFINITY, m1 = -INFINITY, m2 = -INFINITY, m3 = -INFINITY;
  float d0 = 0.f, d1 = 0.f, d2 = 0.f, d3 = 0.f;

  for (int base = start; base < end; base += 64) {
    int cnt = min(64, end - base);
    int sr = 0;
    float e0 = -INFINITY, e1 = -INFINITY, e2 = -INFINITY, e3 = -INFINITY;
    if (lane < cnt) {
      sr = src[base + lane];
      float4 x = el4[sr];
      e0 = lrelu(x.x + er4.x);
      e1 = lrelu(x.y + er4.y);
      e2 = lrelu(x.z + er4.z);
      e3 = lrelu(x.w + er4.w);
    }
    float x0 = e0, x1 = e1, x2 = e2, x3 = e3;
#pragma unroll
    for (int msk = 32; msk >= 1; msk >>= 1) {
      x0 = fmaxf(x0, __shfl_xor(x0, msk));
      x1 = fmaxf(x1, __shfl_xor(x1, msk));
      x2 = fmaxf(x2, __shfl_xor(x2, msk));
      x3 = fmaxf(x3, __shfl_xor(x3, msk));
    }
    float n0 = fmaxf(m0, x0), n1 = fmaxf(m1, x1), n2 = fmaxf(m2, x2), n3 = fmaxf(m3, x3);
    float p0 = 0.f, p1 = 0.f, p2 = 0.f, p3 = 0.f;
    if (lane < cnt) {
      p0 = __expf(e0 - n0); p1 = __expf(e1 - n1);
      p2 = __expf(e2 - n2); p3 = __expf(e3 - n3);
    }
    float s0 = p0, s1 = p1, s2 = p2, s3 = p3;
#pragma unroll
    for (int msk = 32; msk >= 1; msk >>= 1) {
      s0 += __shfl_xor(s0, msk);
      s1 += __shfl_xor(s1, msk);
      s2 += __shfl_xor(s2, msk);
      s3 += __shfl_xor(s3, msk);
    }
    float sc0 = __expf(m0 - n0), sc1 = __expf(m1 - n1);
    float sc2 = __expf(m2 - n2), sc3 = __expf(m3 - n3);
    d0 = d0 * sc0 + s0; d1 = d1 * sc1 + s1;
    d2 = d2 * sc2 + s2; d3 = d3 * sc3 + s3;
    m0 = n0; m1 = n1; m2 = n2; m3 = n3;
    float sch = sel4(sc0, sc1, sc2, sc3, head);
    acc.x *= sch;
    acc.y *= sch;
    *(float4*)&p_sh[wid][lane * 4] = make_float4(p0, p1, p2, p3);
    __builtin_amdgcn_wave_barrier();
    int i = 0;
    for (; i + 1 < cnt; i += 2) {
      int sa = __shfl(sr, i), sb = __shfl(sr, i + 1);
      float pa = p_sh[wid][i * 4 + head];
      float pb = p_sh[wid][(i + 1) * 4 + head];
      float2 va = __half22float2(zp[(size_t)sa * 64 + c]);
      float2 vb = __half22float2(zp[(size_t)sb * 64 + c]);
      acc.x = fmaf(pa, va.x, acc.x); acc.y = fmaf(pa, va.y, acc.y);
      acc.x = fmaf(pb, vb.x, acc.x); acc.y = fmaf(pb, vb.y, acc.y);
    }
    if (i < cnt) {
      int sa = __shfl(sr, i);
      float pa = p_sh[wid][i * 4 + head];
      float2 va = __half22float2(zp[(size_t)sa * 64 + c]);
      acc.x = fmaf(pa, va.x, acc.x); acc.y = fmaf(pa, va.y, acc.y);
    }
    __builtin_amdgcn_wave_barrier();
  }

  float dh = sel4(d0, d1, d2, d3, head);
  float inv = 1.f / fmaxf(dh, 1e-9f);
  float2 bias = reinterpret_cast<const float2*>(b1)[c];
  float v0 = acc.x * inv + bias.x;
  float v1 = acc.y * inv + bias.y;
  v0 = v0 > 0.f ? v0 : __expf(v0) - 1.f;
  v1 = v1 > 0.f ? v1 : __expf(v1) - 1.f;
  reinterpret_cast<float2*>(h1)[(size_t)n * 64 + c] = make_float2(v0, v1);
}

// ---------------- layer-2 projection: wave-per-node ----------------
__global__ __launch_bounds__(256) void proj2_kernel(const float* __restrict__ h1,
                                                    const float* __restrict__ W2,
                                                    const float* __restrict__ al2,
                                                    const float* __restrict__ ar2,
                                                    float4* __restrict__ z2el,
                                                    float* __restrict__ er2) {
  int wid = threadIdx.x >> 6, lane = threadIdx.x & 63;
  int n = blockIdx.x * 4 + wid;
  if (n >= NNODES) return;
  float2 hv = reinterpret_cast<const float2*>(h1)[(size_t)n * 64 + lane];
  int c0 = 2 * lane, c1 = 2 * lane + 1;
  float p0 = hv.x * W2[c0 * 3 + 0] + hv.y * W2[c1 * 3 + 0];
  float p1 = hv.x * W2[c0 * 3 + 1] + hv.y * W2[c1 * 3 + 1];
  float p2 = hv.x * W2[c0 * 3 + 2] + hv.y * W2[c1 * 3 + 2];
#pragma unroll
  for (int msk = 32; msk >= 1; msk >>= 1) {
    p0 += __shfl_xor(p0, msk);
    p1 += __shfl_xor(p1, msk);
    p2 += __shfl_xor(p2, msk);
  }
  if (lane == 0) {
    z2el[n] = make_float4(p0, p1, p2, p0 * al2[0] + p1 * al2[1] + p2 * al2[2]);
    er2[n] = p0 * ar2[0] + p1 * ar2[1] + p2 * ar2[2];
  }
}

// ---------------- layer-2: wave-per-node single-pass softmax + aggregation ----------------
__global__ __launch_bounds__(256) void gat2_agg_kernel(const float4* __restrict__ z2el,
                                                       const float* __restrict__ er2,
                                                       const int* __restrict__ src,
                                                       const int* __restrict__ off,
                                                       const float* __restrict__ b2,
                                                       float* __restrict__ out) {
  int wid = threadIdx.x >> 6, lane = threadIdx.x & 63;
  int n = blockIdx.x * 4 + wid;
  if (n >= NNODES) return;
  int start = off[n], end = off[n + 1];
  float ern = er2[n];
  float m_run = -INFINITY, d_run = 0.f;
  float a0 = 0.f, a1 = 0.f, a2 = 0.f;
  for (int base = start; base < end; base += 64) {
    int cnt = min(64, end - base);
    float4 z4 = make_float4(0.f, 0.f, 0.f, 0.f);
    float e = -INFINITY;
    if (lane < cnt) {
      z4 = z2el[src[base + lane]];
      e = lrelu(z4.w + ern);
    }
    float mx = e;
#pragma unroll
    for (int msk = 32; msk >= 1; msk >>= 1) mx = fmaxf(mx, __shfl_xor(mx, msk));
    float m_new = fmaxf(m_run, mx);
    float p = (lane < cnt) ? __expf(e - m_new) : 0.f;
    float sm = p;
#pragma unroll
    for (int msk = 32; msk >= 1; msk >>= 1) sm += __shfl_xor(sm, msk);
    float scale = __expf(m_run - m_new);
    d_run = d_run * scale + sm;
    a0 = a0 * scale + p * z4.x;
    a1 = a1 * scale + p * z4.y;
    a2 = a2 * scale + p * z4.z;
    m_run = m_new;
  }
#pragma unroll
  for (int msk = 32; msk >= 1; msk >>= 1) {
    a0 += __shfl_xor(a0, msk);
    a1 += __shfl_xor(a1, msk);
    a2 += __shfl_xor(a2, msk);
  }
  if (lane == 0) {
    float inv = 1.f / fmaxf(d_run, 1e-9f);
    out[n * 3 + 0] = a0 * inv + b2[0];
    out[n * 3 + 1] = a1 * inv + b2[1];
    out[n * 3 + 2] = a2 * inv + b2[2];
  }
}

extern "C" void kernel_launch(void* const* d_in, const int* in_sizes, int n_in,
                              void* d_out, int out_size, void* d_ws, size_t ws_size,
                              hipStream_t stream) {
  const float* features = (const float*)d_in[0];
  const int* src = (const int*)d_in[1];
  const int* dst = (const int*)d_in[2];
  const float* W1 = (const float*)d_in[3];
  const float* al1 = (const float*)d_in[4];
  const float* ar1 = (const float*)d_in[5];
  const float* b1 = (const float*)d_in[6];
  const float* W2 = (const float*)d_in[7];
  const float* al2 = (const float*)d_in[8];
  const float* ar2 = (const float*)d_in[9];
  const float* b2 = (const float*)d_in[10];
  float* out = (float*)d_out;
  int E = in_sizes[1];

  char* ws = (char*)d_ws;
  size_t o = 0;
  __half* z1h = (__half*)(ws + o); o += (size_t)NNODES * HID * 2;
  float* h1 = (float*)(ws + o);    o += (size_t)NNODES * HID * 4;
  float* el1 = (float*)(ws + o);   o += (size_t)NNODES * NH * 4;
  float* er1 = (float*)(ws + o);   o += (size_t)NNODES * NH * 4;
  float4* z2el = (float4*)(ws + o); o += (size_t)NNODES * 16;
  float* er2 = (float*)(ws + o);   o += (size_t)NNODES * 4;
  short* BhT = (short*)(ws + o);   o += (size_t)HID * KP * 2;
  short* BlT = (short*)(ws + o);   o += (size_t)HID * KP * 2;
  int* off = (int*)(ws + o);       o += (size_t)(NNODES + 1) * 4;

  convert_w1_kernel<<<256, 256, 0, stream>>>(W1, BhT, BlT);
  gemm1_mfma_kernel<<<(NNODES + BM - 1) / BM, 256, 0, stream>>>(features, BhT, BlT, al1, ar1,
                                                                z1h, el1, er1);
  csr_offsets_kernel<<<(NNODES + 1 + 255) / 256, 256, 0, stream>>>(dst, E, off);
  gat1_agg_kernel<<<(NNODES + 3) / 4, 256, 0, stream>>>(z1h, el1, er1, src, off, b1, h1);
  proj2_kernel<<<(NNODES + 3) / 4, 256, 0, stream>>>(h1, W2, al2, ar2, z2el, er2);
  gat2_agg_kernel<<<(NNODES + 3) / 4, 256, 0, stream>>>(z2el, er2, src, off, b2, out);
}